// Round 1
// baseline (446.357 us; speedup 1.0000x reference)
//
#include <hip/hip_runtime.h>
#include <hip/hip_bf16.h>
#include <cstdint>
#include <cstddef>

#define B_SZ 8
#define S_SZ 4096
#define DM   1024
#define NS   16
#define M_SZ (B_SZ * S_SZ)  // 32768

typedef __attribute__((ext_vector_type(4))) float f32x4;
typedef __attribute__((ext_vector_type(8))) short short8;
typedef __attribute__((ext_vector_type(4))) unsigned short ushort4v;

__device__ __forceinline__ unsigned short f2bf(float f) {
  unsigned u = __float_as_uint(f);
  u += 0x7fffu + ((u >> 16) & 1u);   // RNE
  return (unsigned short)(u >> 16);
}

// ---------------- k0: convert W_o (1024x1024 f32) -> bf16 ----------------
__global__ __launch_bounds__(256) void k0_cvt_wo(const float* __restrict__ Wo,
                                                 unsigned short* __restrict__ out) {
  int i = (blockIdx.x * 256 + threadIdx.x) * 4;
  f32x4 v = *(const f32x4*)(Wo + i);
  ushort4v u;
  u[0] = f2bf(v[0]); u[1] = f2bf(v[1]); u[2] = f2bf(v[2]); u[3] = f2bf(v[3]);
  *(ushort4v*)(out + i) = u;
}

// ---------------- k1: fused delta/Bu/A_exp ----------------
// Per block: 64 consecutive rows (never crossing a batch boundary since S%64==0).
// W_b (fp32, 64KB) + W_t (fp32, 4KB) staged in LDS. Each wave processes 16 rows in
// 4 groups of 4 (register-blocked). Multi-value butterfly reduce: 16 dots in
// 15 shuffles + 2 (vs 96 naive). Outputs written [B,N,S] for the scan kernel.
__global__ __launch_bounds__(256) void k1_proj(
    const float* __restrict__ x, const float* __restrict__ A,
    const float* __restrict__ Wb, const float* __restrict__ bb,
    const float* __restrict__ Wt, const float* __restrict__ bt,
    float* __restrict__ Ae, float* __restrict__ Bu) {
  __shared__ __align__(16) float Wb_s[NS * DM];   // 64 KB
  __shared__ __align__(16) float Wt_s[DM];        // 4 KB
  __shared__ __align__(16) float Bu_s[NS][64];
  __shared__ __align__(16) float Ae_s[NS][64];

  const int tid = threadIdx.x;
#pragma unroll
  for (int i = 0; i < 16; ++i) {
    int fi = tid * 4 + i * 1024;
    *(f32x4*)(Wb_s + fi) = *(const f32x4*)(Wb + fi);
  }
  *(f32x4*)(Wt_s + tid * 4) = *(const f32x4*)(Wt + tid * 4);

  const int lane = tid & 63;
  const int w = tid >> 6;
  const int p = lane & 15;
  const int g = lane >> 4;
  // after the butterfly, lane l holds the dot for n = bitrev4(l&15)
  const int nlane = ((lane & 1) << 3) | (((lane >> 1) & 1) << 2) |
                    (((lane >> 2) & 1) << 1) | ((lane >> 3) & 1);
  const float a_n = A[nlane];
  const float bb_n = bb[nlane];
  const float bt0 = bt[0];

  __syncthreads();

  const int m0 = blockIdx.x * 64;
  const int b_idx = m0 >> 12;          // / S_SZ
  const int s0 = m0 & (S_SZ - 1);
  const int dq = g * 64 + p * 4;       // + q*256 -> covers all 1024 d

#pragma unroll 1
  for (int grp = 0; grp < 4; ++grp) {
    const int rbase = w * 16 + grp * 4;
    f32x4 xr[4][4];
#pragma unroll
    for (int rr = 0; rr < 4; ++rr) {
      const float* xp = x + (size_t)(m0 + rbase + rr) * DM;
#pragma unroll
      for (int q = 0; q < 4; ++q) xr[rr][q] = *(const f32x4*)(xp + q * 256 + dq);
    }
    float bu[16][4];
#pragma unroll
    for (int n = 0; n < 16; ++n)
#pragma unroll
      for (int rr = 0; rr < 4; ++rr) bu[n][rr] = 0.f;
    float da[4] = {0.f, 0.f, 0.f, 0.f};

#pragma unroll
    for (int n = 0; n < 16; ++n) {
#pragma unroll
      for (int q = 0; q < 4; ++q) {
        f32x4 w4 = *(const f32x4*)(Wb_s + n * DM + q * 256 + dq);
#pragma unroll
        for (int e = 0; e < 4; ++e) {
#pragma unroll
          for (int rr = 0; rr < 4; ++rr) bu[n][rr] += w4[e] * xr[rr][q][e];
        }
      }
    }
#pragma unroll
    for (int q = 0; q < 4; ++q) {
      f32x4 t = *(const f32x4*)(Wt_s + q * 256 + dq);
#pragma unroll
      for (int e = 0; e < 4; ++e) {
#pragma unroll
        for (int rr = 0; rr < 4; ++rr) da[rr] += t[e] * xr[rr][q][e];
      }
    }

#pragma unroll
    for (int rr = 0; rr < 4; ++rr) {
      float v[16];
#pragma unroll
      for (int n = 0; n < 16; ++n) v[n] = bu[n][rr];
      // multi-value butterfly: halve live accumulators each step
#pragma unroll
      for (int i = 0; i < 8; ++i) {
        float lo = v[i], hi = v[i + 8];
        float send = (lane & 1) ? lo : hi;
        float got = __shfl_xor(send, 1, 64);
        v[i] = ((lane & 1) ? hi : lo) + got;
      }
#pragma unroll
      for (int i = 0; i < 4; ++i) {
        float lo = v[i], hi = v[i + 4];
        float send = (lane & 2) ? lo : hi;
        float got = __shfl_xor(send, 2, 64);
        v[i] = ((lane & 2) ? hi : lo) + got;
      }
#pragma unroll
      for (int i = 0; i < 2; ++i) {
        float lo = v[i], hi = v[i + 2];
        float send = (lane & 4) ? lo : hi;
        float got = __shfl_xor(send, 4, 64);
        v[i] = ((lane & 4) ? hi : lo) + got;
      }
      {
        float lo = v[0], hi = v[1];
        float send = (lane & 8) ? lo : hi;
        float got = __shfl_xor(send, 8, 64);
        v[0] = ((lane & 8) ? hi : lo) + got;
      }
      float r = v[0];
      r += __shfl_xor(r, 16, 64);
      r += __shfl_xor(r, 32, 64);

      float dsum = da[rr];
#pragma unroll
      for (int mb = 1; mb < 64; mb <<= 1) dsum += __shfl_xor(dsum, mb, 64);
      float z = dsum + bt0;
      float delta = 1.f / (1.f + __expf(-z));
      delta = delta * 0.99f + 0.01f;   // DELTA_SCALE, DELTA_MIN

      if (lane < 16) {
        Bu_s[nlane][rbase + rr] = r + bb_n;
        Ae_s[nlane][rbase + rr] = __expf(a_n * delta);
      }
    }
  }
  __syncthreads();
  {
    int n = tid >> 4;
    int j = (tid & 15) * 4;
    size_t off = ((size_t)(b_idx * NS + n)) * S_SZ + s0 + j;
    *(f32x4*)(Bu + off) = *(const f32x4*)(&Bu_s[n][j]);
    *(f32x4*)(Ae + off) = *(const f32x4*)(&Ae_s[n][j]);
  }
}

// ---------------- k2: associative scan over S ----------------
// 128 independent (b,n) scans. One wave each: 64 segments of 64, wave-level
// Hillis-Steele scan of affine pairs, serial carry. h written [B,S,N].
__global__ __launch_bounds__(64) void k2_scan(const float* __restrict__ Ae,
                                              const float* __restrict__ Bu,
                                              float* __restrict__ h) {
  const int bn = blockIdx.x;
  const int l = threadIdx.x;
  const int b = bn >> 4, n = bn & 15;
  const float* ap = Ae + (size_t)bn * S_SZ;
  const float* up = Bu + (size_t)bn * S_SZ;
  float* hp = h + (size_t)b * S_SZ * NS + n;
  float carry = 0.f;
#pragma unroll 1
  for (int seg = 0; seg < 64; ++seg) {
    float a = ap[seg * 64 + l];
    float u = up[seg * 64 + l];
#pragma unroll
    for (int off = 1; off < 64; off <<= 1) {
      float aL = __shfl_up(a, off, 64);
      float uL = __shfl_up(u, off, 64);
      if (l >= off) { u = a * uL + u; a = aL * a; }
    }
    float hv = a * carry + u;
    hp[(size_t)(seg * 64 + l) * NS] = hv;
    carry = __shfl(hv, 63, 64);
  }
}

// ---------------- k3: y = h @ W_c^T + b_c + x*D -> bf16 ----------------
// Block covers 16 rows; thread owns 4 consecutive d, caches its 4 W_c rows in
// registers (reused across 16 rows -> W_c L2 traffic /16).
__global__ __launch_bounds__(256) void k3_y(
    const float* __restrict__ x, const float* __restrict__ h,
    const float* __restrict__ Wc, const float* __restrict__ bc,
    const float* __restrict__ D, unsigned short* __restrict__ y) {
  const int t = threadIdx.x;
  const int m0 = blockIdx.x * 16;
  const int d0 = t * 4;
  f32x4 wc[4][4];
#pragma unroll
  for (int i = 0; i < 4; ++i)
#pragma unroll
    for (int k = 0; k < 4; ++k) wc[i][k] = *(const f32x4*)(Wc + (d0 + i) * 16 + k * 4);
  f32x4 Dv = *(const f32x4*)(D + d0);
  f32x4 bcv = *(const f32x4*)(bc + d0);
#pragma unroll 1
  for (int mi = 0; mi < 16; ++mi) {
    const int m = m0 + mi;
    const float* hp = h + (size_t)m * NS;
    float hv[16];
    *(f32x4*)(hv) = *(const f32x4*)(hp);
    *(f32x4*)(hv + 4) = *(const f32x4*)(hp + 4);
    *(f32x4*)(hv + 8) = *(const f32x4*)(hp + 8);
    *(f32x4*)(hv + 12) = *(const f32x4*)(hp + 12);
    f32x4 xv = *(const f32x4*)(x + (size_t)m * DM + d0);
    ushort4v u;
#pragma unroll
    for (int i = 0; i < 4; ++i) {
      float s = bcv[i] + xv[i] * Dv[i];
#pragma unroll
      for (int k = 0; k < 16; ++k) s += hv[k] * wc[i][k >> 2][k & 3];
      u[i] = f2bf(s);
    }
    *(ushort4v*)(y + (size_t)m * DM + d0) = u;
  }
}

// ---------------- k4: z = y @ W_o^T + b_o (bf16 MFMA GEMM) ----------------
// m97 structure: 128x128 tile, BK=32, global_load_lds width 16, 4 waves 2x2,
// each wave 4x4 fragments of 16x16x32 bf16 MFMA. Both operands row-major with
// contiguous K ("B^T" form).
__device__ __forceinline__ void gl_lds16(const void* g, void* l) {
  __builtin_amdgcn_global_load_lds(
      (const __attribute__((address_space(1))) void*)g,
      (__attribute__((address_space(3))) void*)l, 16, 0, 0);
}

__global__ __launch_bounds__(256) void k4_gemm(
    const unsigned short* __restrict__ Abf, const unsigned short* __restrict__ Bbf,
    const float* __restrict__ bo, float* __restrict__ C) {
  __shared__ __align__(16) char smem[16384];  // A: [0,8K), B: [8K,16K)
  const int tid = threadIdx.x;
  const int blk = blockIdx.x;
  const int by = blk >> 3;   // 256 m-tiles
  const int bx = blk & 7;    // 8 n-tiles
  const int lane = tid & 63;
  const int w = tid >> 6;
  const int wm = w >> 1, wn = w & 1;
  const int p = lane & 15, g = lane >> 4;

  f32x4 acc[4][4];
#pragma unroll
  for (int i = 0; i < 4; ++i)
#pragma unroll
    for (int j = 0; j < 4; ++j) acc[i][j] = (f32x4){0.f, 0.f, 0.f, 0.f};

  const int chunk0 = tid;
  const int chunk1 = 256 + tid;
  const int rowA0 = chunk0 >> 2, colA0 = chunk0 & 3;
  const int rowA1 = chunk1 >> 2, colA1 = chunk1 & 3;
  const unsigned short* Abase = Abf + (size_t)(by * 128) * DM;
  const unsigned short* Bbase = Bbf + (size_t)(bx * 128) * DM;

#pragma unroll 1
  for (int kk = 0; kk < 32; ++kk) {
    const int k0 = kk * 32;
    gl_lds16(Abase + (size_t)rowA0 * DM + k0 + colA0 * 8, smem + chunk0 * 16);
    gl_lds16(Abase + (size_t)rowA1 * DM + k0 + colA1 * 8, smem + chunk1 * 16);
    gl_lds16(Bbase + (size_t)rowA0 * DM + k0 + colA0 * 8, smem + 8192 + chunk0 * 16);
    gl_lds16(Bbase + (size_t)rowA1 * DM + k0 + colA1 * 8, smem + 8192 + chunk1 * 16);
    __syncthreads();

    short8 af[4], bfr[4];
#pragma unroll
    for (int mi = 0; mi < 4; ++mi)
      af[mi] = *(const short8*)(smem + (wm * 64 + mi * 16 + p) * 64 + g * 16);
#pragma unroll
    for (int ni = 0; ni < 4; ++ni)
      bfr[ni] = *(const short8*)(smem + 8192 + (wn * 64 + ni * 16 + p) * 64 + g * 16);
#pragma unroll
    for (int mi = 0; mi < 4; ++mi)
#pragma unroll
      for (int ni = 0; ni < 4; ++ni)
        acc[mi][ni] = __builtin_amdgcn_mfma_f32_16x16x32_bf16(af[mi], bfr[ni],
                                                              acc[mi][ni], 0, 0, 0);
    __syncthreads();
  }

#pragma unroll
  for (int ni = 0; ni < 4; ++ni) {
    const int c0 = bx * 128 + wn * 64 + ni * 16 + p;
    const float bov = bo[c0];
#pragma unroll
    for (int mi = 0; mi < 4; ++mi) {
      const int r0 = by * 128 + wm * 64 + mi * 16 + g * 4;
#pragma unroll
      for (int r = 0; r < 4; ++r)
        C[(size_t)(r0 + r) * DM + c0] = acc[mi][ni][r] + bov;
    }
  }
}

// ---------------- launch ----------------
extern "C" void kernel_launch(void* const* d_in, const int* in_sizes, int n_in,
                              void* d_out, int out_size, void* d_ws, size_t ws_size,
                              hipStream_t stream) {
  const float* x  = (const float*)d_in[0];
  const float* A  = (const float*)d_in[1];
  const float* Wb = (const float*)d_in[2];
  const float* bb = (const float*)d_in[3];
  const float* Wc = (const float*)d_in[4];
  const float* bc = (const float*)d_in[5];
  const float* D  = (const float*)d_in[6];
  const float* Wt = (const float*)d_in[7];
  const float* bt = (const float*)d_in[8];
  const float* Wo = (const float*)d_in[9];
  const float* bo = (const float*)d_in[10];
  float* out = (float*)d_out;

  char* ws = (char*)d_ws;
  float* Ae = (float*)(ws);                          // 2 MiB  [B,N,S]
  float* Bu = (float*)(ws + (2u << 20));             // 2 MiB  [B,N,S]
  float* h  = (float*)(ws + (4u << 20));             // 2 MiB  [B,S,N]
  unsigned short* Wo16 = (unsigned short*)(ws + (6u << 20));  // 2 MiB
  unsigned short* y16  = (unsigned short*)(ws + (8u << 20));  // 64 MiB

  k0_cvt_wo<<<1024, 256, 0, stream>>>(Wo, Wo16);
  k1_proj<<<512, 256, 0, stream>>>(x, A, Wb, bb, Wt, bt, Ae, Bu);
  k2_scan<<<128, 64, 0, stream>>>(Ae, Bu, h);
  k3_y<<<2048, 256, 0, stream>>>(x, h, Wc, bc, D, y16);
  k4_gemm<<<2048, 256, 0, stream>>>(y16, Wo16, bo, out);
}

// Round 2
// 422.215 us; speedup vs baseline: 1.0572x; 1.0572x over previous
//
#include <hip/hip_runtime.h>
#include <hip/hip_bf16.h>
#include <cstdint>
#include <cstddef>

#define B_SZ 8
#define S_SZ 4096
#define DM   1024
#define NS   16
#define M_SZ (B_SZ * S_SZ)  // 32768

typedef __attribute__((ext_vector_type(4))) float f32x4;
typedef __attribute__((ext_vector_type(8))) short short8;
typedef __attribute__((ext_vector_type(4))) unsigned short ushort4v;

__device__ __forceinline__ unsigned short f2bf(float f) {
  unsigned u = __float_as_uint(f);
  u += 0x7fffu + ((u >> 16) & 1u);   // RNE
  return (unsigned short)(u >> 16);
}

// ---------------- k0_prep: WoD16[o,d]=bf16(Wo*D), Wco16[o,n]=bf16(Wo@Wc), bz[o]=bo+bc@Wo^T
// One block per output row o. Runs AFTER k2 (its outputs alias Ae/Bu scratch).
__global__ __launch_bounds__(256) void k0_prep(
    const float* __restrict__ Wo, const float* __restrict__ D,
    const float* __restrict__ Wc, const float* __restrict__ bc,
    const float* __restrict__ bo, unsigned short* __restrict__ WoD16,
    unsigned short* __restrict__ Wco16, float* __restrict__ bz) {
  const int o = blockIdx.x;
  const int t = threadIdx.x;
  const float* wor = Wo + (size_t)o * DM;

  f32x4 wv = *(const f32x4*)(wor + t * 4);
  f32x4 dv = *(const f32x4*)(D + t * 4);
  ushort4v u;
#pragma unroll
  for (int i = 0; i < 4; ++i) u[i] = f2bf(wv[i] * dv[i]);
  *(ushort4v*)(WoD16 + (size_t)o * DM + t * 4) = u;

  // Wco partials: n = t&15, d-slice ds = t>>4 covers 64 d's
  const int n = t & 15, ds = t >> 4;
  float s = 0.f;
  const float* wod = wor + ds * 64;
  const float* wcd = Wc + (size_t)(ds * 64) * NS + n;
#pragma unroll 8
  for (int j = 0; j < 64; ++j) s += wod[j] * wcd[j * NS];

  // bc @ Wo[o,:] partial over this thread's 4 d's
  f32x4 bcv = *(const f32x4*)(bc + t * 4);
  float pb = wv[0] * bcv[0] + wv[1] * bcv[1] + wv[2] * bcv[2] + wv[3] * bcv[3];

  __shared__ float red[16][17];
  __shared__ float redb[256];
  red[n][ds] = s;
  redb[t] = pb;
  __syncthreads();
  if (t < 16) {
    float acc = 0.f;
#pragma unroll
    for (int k = 0; k < 16; ++k) acc += red[t][k];
    Wco16[(size_t)o * 32 + t] = f2bf(acc);
    Wco16[(size_t)o * 32 + 16 + t] = 0;  // zero-pad K 16..31
  }
  if (t == 0) {
    float b = bo[o];
    for (int i = 0; i < 256; ++i) b += redb[i];
    bz[o] = b;
  }
}

// ---------------- k1: fused delta/Bu/A_exp + x->bf16 ----------------
__global__ __launch_bounds__(256) void k1_proj(
    const float* __restrict__ x, const float* __restrict__ A,
    const float* __restrict__ Wb, const float* __restrict__ bb,
    const float* __restrict__ Wt, const float* __restrict__ bt,
    float* __restrict__ Ae, float* __restrict__ Bu,
    unsigned short* __restrict__ x16) {
  __shared__ __align__(16) float Wb_s[NS * DM];   // 64 KB
  __shared__ __align__(16) float Wt_s[DM];        // 4 KB
  __shared__ __align__(16) float Bu_s[NS][64];
  __shared__ __align__(16) float Ae_s[NS][64];

  const int tid = threadIdx.x;
#pragma unroll
  for (int i = 0; i < 16; ++i) {
    int fi = tid * 4 + i * 1024;
    *(f32x4*)(Wb_s + fi) = *(const f32x4*)(Wb + fi);
  }
  *(f32x4*)(Wt_s + tid * 4) = *(const f32x4*)(Wt + tid * 4);

  const int lane = tid & 63;
  const int w = tid >> 6;
  const int p = lane & 15;
  const int g = lane >> 4;
  const int nlane = ((lane & 1) << 3) | (((lane >> 1) & 1) << 2) |
                    (((lane >> 2) & 1) << 1) | ((lane >> 3) & 1);
  const float a_n = A[nlane];
  const float bb_n = bb[nlane];
  const float bt0 = bt[0];

  __syncthreads();

  const int m0 = blockIdx.x * 64;
  const int b_idx = m0 >> 12;
  const int s0 = m0 & (S_SZ - 1);
  const int dq = g * 64 + p * 4;

#pragma unroll 1
  for (int grp = 0; grp < 4; ++grp) {
    const int rbase = w * 16 + grp * 4;
    f32x4 xr[4][4];
#pragma unroll
    for (int rr = 0; rr < 4; ++rr) {
      const int m = m0 + rbase + rr;
      const float* xp = x + (size_t)m * DM;
#pragma unroll
      for (int q = 0; q < 4; ++q) {
        xr[rr][q] = *(const f32x4*)(xp + q * 256 + dq);
        ushort4v xu;
#pragma unroll
        for (int e = 0; e < 4; ++e) xu[e] = f2bf(xr[rr][q][e]);
        *(ushort4v*)(x16 + (size_t)m * DM + q * 256 + dq) = xu;
      }
    }
    float bu[16][4];
#pragma unroll
    for (int n = 0; n < 16; ++n)
#pragma unroll
      for (int rr = 0; rr < 4; ++rr) bu[n][rr] = 0.f;
    float da[4] = {0.f, 0.f, 0.f, 0.f};

#pragma unroll
    for (int n = 0; n < 16; ++n) {
#pragma unroll
      for (int q = 0; q < 4; ++q) {
        f32x4 w4 = *(const f32x4*)(Wb_s + n * DM + q * 256 + dq);
#pragma unroll
        for (int e = 0; e < 4; ++e) {
#pragma unroll
          for (int rr = 0; rr < 4; ++rr) bu[n][rr] += w4[e] * xr[rr][q][e];
        }
      }
    }
#pragma unroll
    for (int q = 0; q < 4; ++q) {
      f32x4 t = *(const f32x4*)(Wt_s + q * 256 + dq);
#pragma unroll
      for (int e = 0; e < 4; ++e) {
#pragma unroll
        for (int rr = 0; rr < 4; ++rr) da[rr] += t[e] * xr[rr][q][e];
      }
    }

#pragma unroll
    for (int rr = 0; rr < 4; ++rr) {
      float v[16];
#pragma unroll
      for (int n = 0; n < 16; ++n) v[n] = bu[n][rr];
#pragma unroll
      for (int i = 0; i < 8; ++i) {
        float lo = v[i], hi = v[i + 8];
        float send = (lane & 1) ? lo : hi;
        float got = __shfl_xor(send, 1, 64);
        v[i] = ((lane & 1) ? hi : lo) + got;
      }
#pragma unroll
      for (int i = 0; i < 4; ++i) {
        float lo = v[i], hi = v[i + 4];
        float send = (lane & 2) ? lo : hi;
        float got = __shfl_xor(send, 2, 64);
        v[i] = ((lane & 2) ? hi : lo) + got;
      }
#pragma unroll
      for (int i = 0; i < 2; ++i) {
        float lo = v[i], hi = v[i + 2];
        float send = (lane & 4) ? lo : hi;
        float got = __shfl_xor(send, 4, 64);
        v[i] = ((lane & 4) ? hi : lo) + got;
      }
      {
        float lo = v[0], hi = v[1];
        float send = (lane & 8) ? lo : hi;
        float got = __shfl_xor(send, 8, 64);
        v[0] = ((lane & 8) ? hi : lo) + got;
      }
      float r = v[0];
      r += __shfl_xor(r, 16, 64);
      r += __shfl_xor(r, 32, 64);

      float dsum = da[rr];
#pragma unroll
      for (int mb = 1; mb < 64; mb <<= 1) dsum += __shfl_xor(dsum, mb, 64);
      float z = dsum + bt0;
      float delta = 1.f / (1.f + __expf(-z));
      delta = delta * 0.99f + 0.01f;

      if (lane < 16) {
        Bu_s[nlane][rbase + rr] = r + bb_n;
        Ae_s[nlane][rbase + rr] = __expf(a_n * delta);
      }
    }
  }
  __syncthreads();
  {
    int n = tid >> 4;
    int j = (tid & 15) * 4;
    size_t off = ((size_t)(b_idx * NS + n)) * S_SZ + s0 + j;
    *(f32x4*)(Bu + off) = *(const f32x4*)(&Bu_s[n][j]);
    *(f32x4*)(Ae + off) = *(const f32x4*)(&Ae_s[n][j]);
  }
}

// ---------------- k2: associative scan over S, emits h16 [M,32] bf16 ----------------
// 128 independent (b,n) scans; 1 wave each. Next-segment loads prefetched so the
// ~6-step shuffle chain hides the L2 latency.
__global__ __launch_bounds__(64) void k2_scan(const float* __restrict__ Ae,
                                              const float* __restrict__ Bu,
                                              unsigned short* __restrict__ h16) {
  const int bn = blockIdx.x;
  const int l = threadIdx.x;
  const int b = bn >> 4, n = bn & 15;
  const float* ap = Ae + (size_t)bn * S_SZ;
  const float* up = Bu + (size_t)bn * S_SZ;
  unsigned short* hp = h16 + ((size_t)b * S_SZ) * 32 + n;
  float carry = 0.f;
  float a_nx = ap[l];
  float u_nx = up[l];
#pragma unroll 1
  for (int seg = 0; seg < 64; ++seg) {
    float a = a_nx, u = u_nx;
    if (seg < 63) { a_nx = ap[(seg + 1) * 64 + l]; u_nx = up[(seg + 1) * 64 + l]; }
#pragma unroll
    for (int off = 1; off < 64; off <<= 1) {
      float aL = __shfl_up(a, off, 64);
      float uL = __shfl_up(u, off, 64);
      if (l >= off) { u = a * uL + u; a = aL * a; }
    }
    float hv = a * carry + u;
    hp[(size_t)(seg * 64 + l) * 32] = f2bf(hv);
    carry = __shfl(hv, 63, 64);
  }
}

// ---------------- k4: out = x16 @ WoD^T + h16 @ Wco^T + bz (bf16 MFMA) ----------------
__device__ __forceinline__ void gl_lds16(const void* g, void* l) {
  __builtin_amdgcn_global_load_lds(
      (const __attribute__((address_space(1))) void*)g,
      (__attribute__((address_space(3))) void*)l, 16, 0, 0);
}

__global__ __launch_bounds__(256) void k4_gemm(
    const unsigned short* __restrict__ x16, const unsigned short* __restrict__ h16,
    const unsigned short* __restrict__ WoD16, const unsigned short* __restrict__ Wco16,
    const float* __restrict__ bz, float* __restrict__ C) {
  __shared__ __align__(16) char smem[16384];  // A: [0,8K), B: [8K,16K)
  const int tid = threadIdx.x;
  // bijective XCD swizzle (nwg=2048, 2048%8==0): XCD x owns a contiguous run of
  // swizzled ids -> disjoint m-panels per XCD, x16 fetched ~once per panel.
  const int swz = (blockIdx.x & 7) * 256 + (blockIdx.x >> 3);
  const int by = swz >> 3;   // 256 m-tiles
  const int bx = swz & 7;    // 8 n-tiles
  const int lane = tid & 63;
  const int w = tid >> 6;
  const int wm = w >> 1, wn = w & 1;
  const int p = lane & 15, g = lane >> 4;

  f32x4 acc[4][4];
#pragma unroll
  for (int i = 0; i < 4; ++i)
#pragma unroll
    for (int j = 0; j < 4; ++j) acc[i][j] = (f32x4){0.f, 0.f, 0.f, 0.f};

  // --- h-correction: one K=32 step read straight from L2 (h16 2MB, Wco16 64KB) ---
  {
    short8 ah[4], bh[4];
#pragma unroll
    for (int mi = 0; mi < 4; ++mi)
      ah[mi] = *(const short8*)(h16 + (size_t)(by * 128 + wm * 64 + mi * 16 + p) * 32 + g * 8);
#pragma unroll
    for (int ni = 0; ni < 4; ++ni)
      bh[ni] = *(const short8*)(Wco16 + (size_t)(bx * 128 + wn * 64 + ni * 16 + p) * 32 + g * 8);
#pragma unroll
    for (int mi = 0; mi < 4; ++mi)
#pragma unroll
      for (int ni = 0; ni < 4; ++ni)
        acc[mi][ni] = __builtin_amdgcn_mfma_f32_16x16x32_bf16(ah[mi], bh[ni],
                                                              acc[mi][ni], 0, 0, 0);
  }

  const int chunk0 = tid;
  const int chunk1 = 256 + tid;
  const int rowA0 = chunk0 >> 2, colA0 = chunk0 & 3;
  const int rowA1 = chunk1 >> 2, colA1 = chunk1 & 3;
  const unsigned short* Abase = x16 + (size_t)(by * 128) * DM;
  const unsigned short* Bbase = WoD16 + (size_t)(bx * 128) * DM;

#pragma unroll 1
  for (int kk = 0; kk < 32; ++kk) {
    const int k0 = kk * 32;
    gl_lds16(Abase + (size_t)rowA0 * DM + k0 + colA0 * 8, smem + chunk0 * 16);
    gl_lds16(Abase + (size_t)rowA1 * DM + k0 + colA1 * 8, smem + chunk1 * 16);
    gl_lds16(Bbase + (size_t)rowA0 * DM + k0 + colA0 * 8, smem + 8192 + chunk0 * 16);
    gl_lds16(Bbase + (size_t)rowA1 * DM + k0 + colA1 * 8, smem + 8192 + chunk1 * 16);
    __syncthreads();

    short8 af[4], bfr[4];
#pragma unroll
    for (int mi = 0; mi < 4; ++mi)
      af[mi] = *(const short8*)(smem + (wm * 64 + mi * 16 + p) * 64 + g * 16);
#pragma unroll
    for (int ni = 0; ni < 4; ++ni)
      bfr[ni] = *(const short8*)(smem + 8192 + (wn * 64 + ni * 16 + p) * 64 + g * 16);
#pragma unroll
    for (int mi = 0; mi < 4; ++mi)
#pragma unroll
      for (int ni = 0; ni < 4; ++ni)
        acc[mi][ni] = __builtin_amdgcn_mfma_f32_16x16x32_bf16(af[mi], bfr[ni],
                                                              acc[mi][ni], 0, 0, 0);
    __syncthreads();
  }

#pragma unroll
  for (int ni = 0; ni < 4; ++ni) {
    const int c0 = bx * 128 + wn * 64 + ni * 16 + p;
    const float bzv = bz[c0];
#pragma unroll
    for (int mi = 0; mi < 4; ++mi) {
      const int r0 = by * 128 + wm * 64 + mi * 16 + g * 4;
#pragma unroll
      for (int r = 0; r < 4; ++r)
        C[(size_t)(r0 + r) * DM + c0] = acc[mi][ni][r] + bzv;
    }
  }
}

// ---------------- launch ----------------
extern "C" void kernel_launch(void* const* d_in, const int* in_sizes, int n_in,
                              void* d_out, int out_size, void* d_ws, size_t ws_size,
                              hipStream_t stream) {
  const float* x  = (const float*)d_in[0];
  const float* A  = (const float*)d_in[1];
  const float* Wb = (const float*)d_in[2];
  const float* bb = (const float*)d_in[3];
  const float* Wc = (const float*)d_in[4];
  const float* bc = (const float*)d_in[5];
  const float* D  = (const float*)d_in[6];
  const float* Wt = (const float*)d_in[7];
  const float* bt = (const float*)d_in[8];
  const float* Wo = (const float*)d_in[9];
  const float* bo = (const float*)d_in[10];
  float* out = (float*)d_out;

  char* ws = (char*)d_ws;
  // region0 [0,2M):   Ae (k1->k2), then WoD16 (k0_prep->k4)   [aliased lifetimes]
  // region1 [2M,4M):  Bu (k1->k2), then Wco16+bz (k0_prep->k4)
  // region2 [4M,6M):  h16 [M,32] bf16
  // region3 [6M,70M): x16 [M,1024] bf16
  float* Ae = (float*)(ws);
  float* Bu = (float*)(ws + (2u << 20));
  unsigned short* WoD16 = (unsigned short*)(ws);
  unsigned short* Wco16 = (unsigned short*)(ws + (2u << 20));
  float* bz = (float*)(ws + (2u << 20) + (64u << 10));
  unsigned short* h16 = (unsigned short*)(ws + (4u << 20));
  unsigned short* x16 = (unsigned short*)(ws + (6u << 20));

  k1_proj<<<512, 256, 0, stream>>>(x, A, Wb, bb, Wt, bt, Ae, Bu, x16);
  hipMemsetAsync(h16, 0, (size_t)M_SZ * 32 * 2, stream);
  k2_scan<<<128, 64, 0, stream>>>(Ae, Bu, h16);
  k0_prep<<<1024, 256, 0, stream>>>(Wo, D, Wc, bc, bo, WoD16, Wco16, bz);
  k4_gemm<<<2048, 256, 0, stream>>>(x16, h16, WoD16, Wco16, bz, out);
}

// Round 3
// 366.169 us; speedup vs baseline: 1.2190x; 1.1531x over previous
//
#include <hip/hip_runtime.h>
#include <hip/hip_bf16.h>
#include <cstdint>
#include <cstddef>

#define B_SZ 8
#define S_SZ 4096
#define DM   1024
#define NS   16
#define M_SZ (B_SZ * S_SZ)  // 32768

typedef __attribute__((ext_vector_type(4))) float f32x4;
typedef __attribute__((ext_vector_type(8))) short short8;
typedef __attribute__((ext_vector_type(4))) unsigned short ushort4v;
typedef __attribute__((ext_vector_type(8))) unsigned short ushort8v;

__device__ __forceinline__ unsigned short f2bf(float f) {
  unsigned u = __float_as_uint(f);
  u += 0x7fffu + ((u >> 16) & 1u);   // RNE
  return (unsigned short)(u >> 16);
}

__device__ __forceinline__ short8 cvt8(f32x4 a, f32x4 b) {
  short8 r;
  r[0] = (short)f2bf(a[0]); r[1] = (short)f2bf(a[1]);
  r[2] = (short)f2bf(a[2]); r[3] = (short)f2bf(a[3]);
  r[4] = (short)f2bf(b[0]); r[5] = (short)f2bf(b[1]);
  r[6] = (short)f2bf(b[2]); r[7] = (short)f2bf(b[3]);
  return r;
}

__device__ __forceinline__ void gl_lds16(const void* g, void* l) {
  __builtin_amdgcn_global_load_lds(
      (const __attribute__((address_space(1))) void*)g,
      (__attribute__((address_space(3))) void*)l, 16, 0, 0);
}

// ---------------- kW: build W'[32][1024] bf16, XOR-swizzled, in global ----------------
// row 0..15 = W_b, row 16 = W_t, rows 17..31 = 0. Byte layout matches what k1
// wants in LDS after a LINEAR copy: elem(col,k) at byte (col*2048 + k*2) ^ ((col&7)<<4).
__global__ __launch_bounds__(128) void kW(const float* __restrict__ Wb,
                                          const float* __restrict__ Wt,
                                          unsigned short* __restrict__ W16s) {
  const int col = blockIdx.x;    // 0..31
  const int k8 = threadIdx.x;    // 0..127 -> k = k8*8..+7
  f32x4 a = {0.f, 0.f, 0.f, 0.f}, b = {0.f, 0.f, 0.f, 0.f};
  if (col < 16) {
    a = *(const f32x4*)(Wb + (size_t)col * DM + k8 * 8);
    b = *(const f32x4*)(Wb + (size_t)col * DM + k8 * 8 + 4);
  } else if (col == 16) {
    a = *(const f32x4*)(Wt + k8 * 8);
    b = *(const f32x4*)(Wt + k8 * 8 + 4);
  }
  short8 v = cvt8(a, b);
  const int byteoff = (col * 2048 + k8 * 16) ^ ((col & 7) << 4);
  *(short8*)((char*)W16s + byteoff) = v;
}

// ---------------- k0_prep: WoD16, Wco16, bz (independent of data path) ----------------
__global__ __launch_bounds__(256) void k0_prep(
    const float* __restrict__ Wo, const float* __restrict__ D,
    const float* __restrict__ Wc, const float* __restrict__ bc,
    const float* __restrict__ bo, unsigned short* __restrict__ WoD16,
    unsigned short* __restrict__ Wco16, float* __restrict__ bz) {
  const int o = blockIdx.x;
  const int t = threadIdx.x;
  const float* wor = Wo + (size_t)o * DM;

  f32x4 wv = *(const f32x4*)(wor + t * 4);
  f32x4 dv = *(const f32x4*)(D + t * 4);
  ushort4v u;
#pragma unroll
  for (int i = 0; i < 4; ++i) u[i] = f2bf(wv[i] * dv[i]);
  *(ushort4v*)(WoD16 + (size_t)o * DM + t * 4) = u;

  const int n = t & 15, ds = t >> 4;
  float s = 0.f;
  const float* wod = wor + ds * 64;
  const float* wcd = Wc + (size_t)(ds * 64) * NS + n;
#pragma unroll 8
  for (int j = 0; j < 64; ++j) s += wod[j] * wcd[j * NS];

  f32x4 bcv = *(const f32x4*)(bc + t * 4);
  float pb = wv[0] * bcv[0] + wv[1] * bcv[1] + wv[2] * bcv[2] + wv[3] * bcv[3];

  __shared__ float red[16][17];
  __shared__ float redb[256];
  red[n][ds] = s;
  redb[t] = pb;
  __syncthreads();
  if (t < 16) {
    float acc = 0.f;
#pragma unroll
    for (int k = 0; k < 16; ++k) acc += red[t][k];
    Wco16[(size_t)o * 32 + t] = f2bf(acc);
    Wco16[(size_t)o * 32 + 16 + t] = 0;
  }
  if (t == 0) {
    float b = bo[o];
    for (int i = 0; i < 256; ++i) b += redb[i];
    bz[o] = b;
  }
}

// ---------------- k1: MFMA skinny GEMM: Bu/z + x->bf16 ----------------
// Block = 64 rows, 4 waves (wave -> 16 rows). A-frags loaded lane-direct from x
// (f32, converted in regs -> also stored to x16). B = W' from LDS (XOR-swizzled).
// acc0 = cols 0..15 (Bu), acc1 col 16 = delta-logit.
__global__ __launch_bounds__(256) void k1_proj(
    const float* __restrict__ x, const float* __restrict__ A,
    const unsigned short* __restrict__ W16s,
    const float* __restrict__ bb, const float* __restrict__ bt,
    float* __restrict__ Ae, float* __restrict__ Bu,
    unsigned short* __restrict__ x16) {
  __shared__ __align__(16) char Wlds[65536];
  __shared__ float Bu_s[16][65];
  __shared__ float z_s[64];
  const int tid = threadIdx.x, lane = tid & 63, w = tid >> 6;
  const int p = lane & 15, g = lane >> 4;

#pragma unroll
  for (int i = 0; i < 16; ++i)
    gl_lds16((const char*)W16s + (w * 16 + i) * 1024 + lane * 16,
             Wlds + (w * 16 + i) * 1024);
  __syncthreads();

  const int m0 = blockIdx.x * 64;
  const int m = m0 + w * 16 + p;
  const float* xp = x + (size_t)m * DM;
  unsigned short* xo = x16 + (size_t)m * DM;
  f32x4 acc0 = {0.f, 0.f, 0.f, 0.f}, acc1 = {0.f, 0.f, 0.f, 0.f};
  const int cb0 = p * 2048;
  const int cb1 = (16 + p) * 2048;
  const int sw0 = (p & 7) << 4;   // (16+p)&7 == p&7

#pragma unroll 2
  for (int kk = 0; kk < 32; ++kk) {
    const int k0 = kk * 32 + g * 8;
    f32x4 xa = *(const f32x4*)(xp + k0);
    f32x4 xb = *(const f32x4*)(xp + k0 + 4);
    short8 af = cvt8(xa, xb);
    *(short8*)(xo + k0) = af;
    const int kb = kk * 64 + g * 16;
    short8 b0 = *(const short8*)(Wlds + ((cb0 + kb) ^ sw0));
    short8 b1 = *(const short8*)(Wlds + ((cb1 + kb) ^ sw0));
    acc0 = __builtin_amdgcn_mfma_f32_16x16x32_bf16(af, b0, acc0, 0, 0, 0);
    acc1 = __builtin_amdgcn_mfma_f32_16x16x32_bf16(af, b1, acc1, 0, 0, 0);
  }

  // epilogue: C layout col=lane&15, row=(lane>>4)*4+r
  const float bbn = bb[p];
#pragma unroll
  for (int r = 0; r < 4; ++r) Bu_s[p][w * 16 + g * 4 + r] = acc0[r] + bbn;
  if (p == 0) {
#pragma unroll
    for (int r = 0; r < 4; ++r) z_s[w * 16 + g * 4 + r] = acc1[r];
  }
  __syncthreads();

  const int b_idx = m0 >> 12;
  const int s0 = m0 & (S_SZ - 1);
  const int n = tid >> 4, j0 = (tid & 15) * 4;
  const float an = A[n];
  const float bt0 = bt[0];
  size_t off = ((size_t)(b_idx * NS + n)) * S_SZ + s0 + j0;
#pragma unroll
  for (int jj = 0; jj < 4; ++jj) {
    float z = z_s[j0 + jj] + bt0;
    float delta = 1.f / (1.f + __expf(-z));
    delta = delta * 0.99f + 0.01f;
    Ae[off + jj] = __expf(an * delta);
    Bu[off + jj] = Bu_s[n][j0 + jj];
  }
}

// ---------------- k2a: per-chunk local affine scan (in-place) ----------------
// 2048 chunks of 256; wave per chunk. Writes (A_cum, U) over (Ae, Bu); chunk
// aggregates to agg_a/agg_u.
__global__ __launch_bounds__(256) void k2a(float* __restrict__ Ae, float* __restrict__ Bu,
                                           float* __restrict__ agg_a, float* __restrict__ agg_u) {
  const int l = threadIdx.x & 63, w = threadIdx.x >> 6;
  const int cid = blockIdx.x * 4 + w;        // [B,N,S] tiles linearly into 256-chunks
  float* ap = Ae + (size_t)cid * 256;
  float* up = Bu + (size_t)cid * 256;
  float ca = 1.f, cu = 0.f;
#pragma unroll 1
  for (int seg = 0; seg < 4; ++seg) {
    float a = ap[seg * 64 + l], u = up[seg * 64 + l];
#pragma unroll
    for (int off = 1; off < 64; off <<= 1) {
      float aL = __shfl_up(a, off, 64);
      float uL = __shfl_up(u, off, 64);
      if (l >= off) { u = a * uL + u; a = aL * a; }
    }
    float At = ca * a, Ut = a * cu + u;
    ap[seg * 64 + l] = At;
    up[seg * 64 + l] = Ut;
    ca = __shfl(At, 63, 64);
    cu = __shfl(Ut, 63, 64);
  }
  if (l == 0) { agg_a[cid] = ca; agg_u[cid] = cu; }
}

// ---------------- k2b: scan chunk aggregates -> exclusive chunk carries ----------------
__global__ __launch_bounds__(128) void k2b(const float* __restrict__ agg_a,
                                           const float* __restrict__ agg_u,
                                           float* __restrict__ cpre) {
  const int t = threadIdx.x;  // bn = 0..127
  float cu = 0.f;
#pragma unroll
  for (int c = 0; c < 16; ++c) {
    cpre[t * 16 + c] = cu;
    cu = agg_a[t * 16 + c] * cu + agg_u[t * 16 + c];
  }
}

// ---------------- k2c: h = A_cum*carry + U, transpose to h16 [M,32] bf16 ----------------
__global__ __launch_bounds__(256) void k2c(const float* __restrict__ Ae,
                                           const float* __restrict__ Bu,
                                           const float* __restrict__ cpre,
                                           unsigned short* __restrict__ h16) {
  const int m = blockIdx.x * 256 + threadIdx.x;
  const int b = m >> 12, s = m & 4095, c = s >> 8;
  unsigned short o[32];
#pragma unroll
  for (int n = 0; n < 16; ++n) {
    size_t idx = ((size_t)(b * 16 + n)) * 4096 + s;
    float h = Ae[idx] * cpre[(b * 16 + n) * 16 + c] + Bu[idx];
    o[n] = f2bf(h);
  }
#pragma unroll
  for (int n = 16; n < 32; ++n) o[n] = 0;
  unsigned short* dst = h16 + (size_t)m * 32;
#pragma unroll
  for (int q = 0; q < 4; ++q) *(ushort8v*)(dst + q * 8) = *(const ushort8v*)(o + q * 8);
}

// ---------------- k4: out = x16 @ WoD^T + h16 @ Wco^T + bz (bf16 MFMA) ----------------
// m97 128x128 tile + minimal 2-phase pipeline: double-buffered LDS, stage k+1
// BEFORE compute of k, one barrier per iteration (drain after MFMA).
__global__ __launch_bounds__(256) void k4_gemm(
    const unsigned short* __restrict__ x16, const unsigned short* __restrict__ h16,
    const unsigned short* __restrict__ WoD16, const unsigned short* __restrict__ Wco16,
    const float* __restrict__ bz, float* __restrict__ C) {
  __shared__ __align__(16) char smem[32768];  // two 16KB buffers: {A 8K | B 8K}
  const int tid = threadIdx.x;
  const int swz = (blockIdx.x & 7) * 256 + (blockIdx.x >> 3);  // bijective XCD swizzle
  const int by = swz >> 3;
  const int bx = swz & 7;
  const int lane = tid & 63;
  const int w = tid >> 6;
  const int wm = w >> 1, wn = w & 1;
  const int p = lane & 15, g = lane >> 4;

  f32x4 acc[4][4];
#pragma unroll
  for (int i = 0; i < 4; ++i)
#pragma unroll
    for (int j = 0; j < 4; ++j) acc[i][j] = (f32x4){0.f, 0.f, 0.f, 0.f};

  // h-correction: one K=32 MFMA step straight from L2 (h16 2MB, Wco16 64KB)
  {
    short8 ah[4], bh[4];
#pragma unroll
    for (int mi = 0; mi < 4; ++mi)
      ah[mi] = *(const short8*)(h16 + (size_t)(by * 128 + wm * 64 + mi * 16 + p) * 32 + g * 8);
#pragma unroll
    for (int ni = 0; ni < 4; ++ni)
      bh[ni] = *(const short8*)(Wco16 + (size_t)(bx * 128 + wn * 64 + ni * 16 + p) * 32 + g * 8);
#pragma unroll
    for (int mi = 0; mi < 4; ++mi)
#pragma unroll
      for (int ni = 0; ni < 4; ++ni)
        acc[mi][ni] = __builtin_amdgcn_mfma_f32_16x16x32_bf16(ah[mi], bh[ni],
                                                              acc[mi][ni], 0, 0, 0);
  }

  const int chunk0 = tid;
  const int chunk1 = 256 + tid;
  const int rowA0 = chunk0 >> 2, colA0 = chunk0 & 3;
  const int rowA1 = chunk1 >> 2, colA1 = chunk1 & 3;
  const unsigned short* Abase = x16 + (size_t)(by * 128) * DM;
  const unsigned short* Bbase = WoD16 + (size_t)(bx * 128) * DM;

#define STAGE(buf, kk)                                                              \
  do {                                                                              \
    char* sb = smem + (buf) * 16384;                                                \
    const int k0_ = (kk) * 32;                                                      \
    gl_lds16(Abase + (size_t)rowA0 * DM + k0_ + colA0 * 8, sb + chunk0 * 16);       \
    gl_lds16(Abase + (size_t)rowA1 * DM + k0_ + colA1 * 8, sb + chunk1 * 16);       \
    gl_lds16(Bbase + (size_t)rowA0 * DM + k0_ + colA0 * 8, sb + 8192 + chunk0 * 16);\
    gl_lds16(Bbase + (size_t)rowA1 * DM + k0_ + colA1 * 8, sb + 8192 + chunk1 * 16);\
  } while (0)

  STAGE(0, 0);
  __syncthreads();
  int cur = 0;
#pragma unroll 1
  for (int kk = 0; kk < 32; ++kk) {
    if (kk < 31) STAGE(cur ^ 1, kk + 1);
    const char* sb = smem + cur * 16384;
    short8 af[4], bfr[4];
#pragma unroll
    for (int mi = 0; mi < 4; ++mi)
      af[mi] = *(const short8*)(sb + (wm * 64 + mi * 16 + p) * 64 + g * 16);
#pragma unroll
    for (int ni = 0; ni < 4; ++ni)
      bfr[ni] = *(const short8*)(sb + 8192 + (wn * 64 + ni * 16 + p) * 64 + g * 16);
#pragma unroll
    for (int mi = 0; mi < 4; ++mi)
#pragma unroll
      for (int ni = 0; ni < 4; ++ni)
        acc[mi][ni] = __builtin_amdgcn_mfma_f32_16x16x32_bf16(af[mi], bfr[ni],
                                                              acc[mi][ni], 0, 0, 0);
    __syncthreads();
    cur ^= 1;
  }
#undef STAGE

#pragma unroll
  for (int ni = 0; ni < 4; ++ni) {
    const int c0 = bx * 128 + wn * 64 + ni * 16 + p;
    const float bzv = bz[c0];
#pragma unroll
    for (int mi = 0; mi < 4; ++mi) {
      const int r0 = by * 128 + wm * 64 + mi * 16 + g * 4;
#pragma unroll
      for (int r = 0; r < 4; ++r)
        C[(size_t)(r0 + r) * DM + c0] = acc[mi][ni][r] + bzv;
    }
  }
}

// ---------------- launch ----------------
extern "C" void kernel_launch(void* const* d_in, const int* in_sizes, int n_in,
                              void* d_out, int out_size, void* d_ws, size_t ws_size,
                              hipStream_t stream) {
  const float* x  = (const float*)d_in[0];
  const float* A  = (const float*)d_in[1];
  const float* Wb = (const float*)d_in[2];
  const float* bb = (const float*)d_in[3];
  const float* Wc = (const float*)d_in[4];
  const float* bc = (const float*)d_in[5];
  const float* D  = (const float*)d_in[6];
  const float* Wt = (const float*)d_in[7];
  const float* bt = (const float*)d_in[8];
  const float* Wo = (const float*)d_in[9];
  const float* bo = (const float*)d_in[10];
  float* out = (float*)d_out;

  char* ws = (char*)d_ws;
  float* Ae            = (float*)(ws);                              // 2 MiB [B,N,S]
  float* Bu            = (float*)(ws + (2u << 20));                 // 2 MiB [B,N,S]
  unsigned short* h16  = (unsigned short*)(ws + (4u << 20));        // 2 MiB [M,32]
  unsigned short* WoD16= (unsigned short*)(ws + (6u << 20));        // 2 MiB
  unsigned short* Wco16= (unsigned short*)(ws + (8u << 20));        // 64 KiB
  float* bz            = (float*)(ws + (8u << 20) + (64u << 10));   // 4 KiB
  unsigned short* W16s = (unsigned short*)(ws + (8u << 20) + (68u << 10)); // 64 KiB
  float* agg_a         = (float*)(ws + (8u << 20) + (132u << 10));  // 8 KiB
  float* agg_u         = (float*)(ws + (8u << 20) + (140u << 10));  // 8 KiB
  float* cpre          = (float*)(ws + (8u << 20) + (148u << 10));  // 8 KiB
  unsigned short* x16  = (unsigned short*)(ws + (9u << 20));        // 64 MiB

  kW<<<32, 128, 0, stream>>>(Wb, Wt, W16s);
  k0_prep<<<1024, 256, 0, stream>>>(Wo, D, Wc, bc, bo, WoD16, Wco16, bz);
  k1_proj<<<512, 256, 0, stream>>>(x, A, W16s, bb, bt, Ae, Bu, x16);
  k2a<<<512, 256, 0, stream>>>(Ae, Bu, agg_a, agg_u);
  k2b<<<1, 128, 0, stream>>>(agg_a, agg_u, cpre);
  k2c<<<128, 256, 0, stream>>>(Ae, Bu, cpre, h16);
  k4_gemm<<<2048, 256, 0, stream>>>(x16, h16, WoD16, Wco16, bz, out);
}

// Round 4
// 355.962 us; speedup vs baseline: 1.2539x; 1.0287x over previous
//
#include <hip/hip_runtime.h>
#include <hip/hip_bf16.h>
#include <cstdint>
#include <cstddef>

#define B_SZ 8
#define S_SZ 4096
#define DM   1024
#define NS   16
#define M_SZ (B_SZ * S_SZ)  // 32768

typedef __attribute__((ext_vector_type(4))) float f32x4;
typedef __attribute__((ext_vector_type(8))) short short8;
typedef __attribute__((ext_vector_type(4))) unsigned short ushort4v;
typedef __attribute__((ext_vector_type(8))) unsigned short ushort8v;

__device__ __forceinline__ unsigned short f2bf(float f) {
  unsigned u = __float_as_uint(f);
  u += 0x7fffu + ((u >> 16) & 1u);   // RNE
  return (unsigned short)(u >> 16);
}

__device__ __forceinline__ short8 cvt8(f32x4 a, f32x4 b) {
  short8 r;
  r[0] = (short)f2bf(a[0]); r[1] = (short)f2bf(a[1]);
  r[2] = (short)f2bf(a[2]); r[3] = (short)f2bf(a[3]);
  r[4] = (short)f2bf(b[0]); r[5] = (short)f2bf(b[1]);
  r[6] = (short)f2bf(b[2]); r[7] = (short)f2bf(b[3]);
  return r;
}

__device__ __forceinline__ void gl_lds16(const void* g, void* l) {
  __builtin_amdgcn_global_load_lds(
      (const __attribute__((address_space(1))) void*)g,
      (__attribute__((address_space(3))) void*)l, 16, 0, 0);
}

#define SB() __builtin_amdgcn_sched_barrier(0)
__device__ __forceinline__ void bar() { SB(); __builtin_amdgcn_s_barrier(); SB(); }
#define VMW4 asm volatile("s_waitcnt vmcnt(4)" ::: "memory")
#define VMW0 asm volatile("s_waitcnt vmcnt(0)" ::: "memory")
#define VMNOP (void)0

// ---------------- k0_prep (+ folded kW) ----------------
// blocks 0..1023: WoD16[o,:]=bf16(Wo*D); Wco16[o,:]=bf16(Wo@Wc) zero-padded to K=32;
//                 bz[o]=bo+bc@Wo[o,:].
// blocks 1024..1055: build W'[32][1024] bf16 XOR-swizzled (rows 0-15 W_b, 16 W_t, rest 0).
__global__ __launch_bounds__(256) void k0_prep(
    const float* __restrict__ Wo, const float* __restrict__ D,
    const float* __restrict__ Wc, const float* __restrict__ bc,
    const float* __restrict__ bo, unsigned short* __restrict__ WoD16,
    unsigned short* __restrict__ Wco16, float* __restrict__ bz,
    const float* __restrict__ Wb, const float* __restrict__ Wt,
    unsigned short* __restrict__ W16s) {
  const int t = threadIdx.x;
  if (blockIdx.x >= 1024) {   // kW part
    const int col = blockIdx.x - 1024;
    f32x4 a = {0.f, 0.f, 0.f, 0.f};
    if (col < 16)       a = *(const f32x4*)(Wb + (size_t)col * DM + t * 4);
    else if (col == 16) a = *(const f32x4*)(Wt + t * 4);
    ushort4v u;
#pragma unroll
    for (int i = 0; i < 4; ++i) u[i] = f2bf(a[i]);
    *(ushort4v*)((char*)W16s + ((col * 2048 + t * 8) ^ ((col & 7) << 4))) = u;
    return;
  }
  const int o = blockIdx.x;
  const float* wor = Wo + (size_t)o * DM;

  f32x4 wv = *(const f32x4*)(wor + t * 4);
  f32x4 dv = *(const f32x4*)(D + t * 4);
  ushort4v u;
#pragma unroll
  for (int i = 0; i < 4; ++i) u[i] = f2bf(wv[i] * dv[i]);
  *(ushort4v*)(WoD16 + (size_t)o * DM + t * 4) = u;

  const int n = t & 15, ds = t >> 4;
  float s = 0.f;
  const float* wod = wor + ds * 64;
  const float* wcd = Wc + (size_t)(ds * 64) * NS + n;
#pragma unroll 8
  for (int j = 0; j < 64; ++j) s += wod[j] * wcd[j * NS];

  f32x4 bcv = *(const f32x4*)(bc + t * 4);
  float pb = wv[0] * bcv[0] + wv[1] * bcv[1] + wv[2] * bcv[2] + wv[3] * bcv[3];

  __shared__ float red[16][17];
  __shared__ float redb[256];
  red[n][ds] = s;
  redb[t] = pb;
  __syncthreads();
  if (t < 16) {
    float acc = 0.f;
#pragma unroll
    for (int k = 0; k < 16; ++k) acc += red[t][k];
    Wco16[(size_t)o * 32 + t] = f2bf(acc);
    Wco16[(size_t)o * 32 + 16 + t] = 0;
  }
  if (t < 64) {
    float s4 = redb[t] + redb[t + 64] + redb[t + 128] + redb[t + 192];
#pragma unroll
    for (int mb = 1; mb < 64; mb <<= 1) s4 += __shfl_xor(s4, mb, 64);
    if (t == 0) bz[o] = bo[o] + s4;
  }
}

// ---------------- k1: MFMA skinny GEMM: Bu/z + x->bf16 ----------------
__global__ __launch_bounds__(256) void k1_proj(
    const float* __restrict__ x, const float* __restrict__ A,
    const unsigned short* __restrict__ W16s,
    const float* __restrict__ bb, const float* __restrict__ bt,
    float* __restrict__ Ae, float* __restrict__ Bu,
    unsigned short* __restrict__ x16) {
  __shared__ __align__(16) char Wlds[65536];
  __shared__ float Bu_s[16][65];
  __shared__ float z_s[64];
  const int tid = threadIdx.x, lane = tid & 63, w = tid >> 6;
  const int p = lane & 15, g = lane >> 4;

#pragma unroll
  for (int i = 0; i < 16; ++i)
    gl_lds16((const char*)W16s + (w * 16 + i) * 1024 + lane * 16,
             Wlds + (w * 16 + i) * 1024);
  __syncthreads();

  const int m0 = blockIdx.x * 64;
  const int m = m0 + w * 16 + p;
  const float* xp = x + (size_t)m * DM;
  unsigned short* xo = x16 + (size_t)m * DM;
  f32x4 acc0 = {0.f, 0.f, 0.f, 0.f}, acc1 = {0.f, 0.f, 0.f, 0.f};
  const int cb0 = p * 2048;
  const int cb1 = (16 + p) * 2048;
  const int sw0 = (p & 7) << 4;

#pragma unroll 2
  for (int kk = 0; kk < 32; ++kk) {
    const int k0 = kk * 32 + g * 8;
    f32x4 xa = *(const f32x4*)(xp + k0);
    f32x4 xb = *(const f32x4*)(xp + k0 + 4);
    short8 af = cvt8(xa, xb);
    *(short8*)(xo + k0) = af;
    const int kb = kk * 64 + g * 16;
    short8 b0 = *(const short8*)(Wlds + ((cb0 + kb) ^ sw0));
    short8 b1 = *(const short8*)(Wlds + ((cb1 + kb) ^ sw0));
    acc0 = __builtin_amdgcn_mfma_f32_16x16x32_bf16(af, b0, acc0, 0, 0, 0);
    acc1 = __builtin_amdgcn_mfma_f32_16x16x32_bf16(af, b1, acc1, 0, 0, 0);
  }

  const float bbn = bb[p];
#pragma unroll
  for (int r = 0; r < 4; ++r) Bu_s[p][w * 16 + g * 4 + r] = acc0[r] + bbn;
  if (p == 0) {
#pragma unroll
    for (int r = 0; r < 4; ++r) z_s[w * 16 + g * 4 + r] = acc1[r];
  }
  __syncthreads();

  const int b_idx = m0 >> 12;
  const int s0 = m0 & (S_SZ - 1);
  const int n = tid >> 4, j0 = (tid & 15) * 4;
  const float an = A[n];
  const float bt0 = bt[0];
  size_t off = ((size_t)(b_idx * NS + n)) * S_SZ + s0 + j0;
#pragma unroll
  for (int jj = 0; jj < 4; ++jj) {
    float z = z_s[j0 + jj] + bt0;
    float delta = 1.f / (1.f + __expf(-z));
    delta = delta * 0.99f + 0.01f;
    Ae[off + jj] = __expf(an * delta);
    Bu[off + jj] = Bu_s[n][j0 + jj];
  }
}

// ---------------- k2a: per-chunk local affine scan (in-place) ----------------
__global__ __launch_bounds__(256) void k2a(float* __restrict__ Ae, float* __restrict__ Bu,
                                           float* __restrict__ agg_a, float* __restrict__ agg_u) {
  const int l = threadIdx.x & 63, w = threadIdx.x >> 6;
  const int cid = blockIdx.x * 4 + w;
  float* ap = Ae + (size_t)cid * 256;
  float* up = Bu + (size_t)cid * 256;
  float ca = 1.f, cu = 0.f;
#pragma unroll 1
  for (int seg = 0; seg < 4; ++seg) {
    float a = ap[seg * 64 + l], u = up[seg * 64 + l];
#pragma unroll
    for (int off = 1; off < 64; off <<= 1) {
      float aL = __shfl_up(a, off, 64);
      float uL = __shfl_up(u, off, 64);
      if (l >= off) { u = a * uL + u; a = aL * a; }
    }
    float At = ca * a, Ut = a * cu + u;
    ap[seg * 64 + l] = At;
    up[seg * 64 + l] = Ut;
    ca = __shfl(At, 63, 64);
    cu = __shfl(Ut, 63, 64);
  }
  if (l == 0) { agg_a[cid] = ca; agg_u[cid] = cu; }
}

// ---------------- k2c: carries (folded k2b) + h16 [M,32] bf16 ----------------
__global__ __launch_bounds__(256) void k2c(const float* __restrict__ Ae,
                                           const float* __restrict__ Bu,
                                           const float* __restrict__ agg_a,
                                           const float* __restrict__ agg_u,
                                           unsigned short* __restrict__ h16) {
  const int t = threadIdx.x;
  const int m = blockIdx.x * 256 + t;
  const int b = m >> 12, s = m & 4095, c = s >> 8;
  __shared__ float cp_s[16];
  if (t < 16) {
    float cu = 0.f;
    const int base = (b * 16 + t) * 16;
    for (int c2 = 0; c2 < c; ++c2) cu = agg_a[base + c2] * cu + agg_u[base + c2];
    cp_s[t] = cu;
  }
  __syncthreads();
  unsigned short o[32];
#pragma unroll
  for (int n = 0; n < 16; ++n) {
    size_t idx = ((size_t)(b * 16 + n)) * 4096 + s;
    float h = Ae[idx] * cp_s[n] + Bu[idx];
    o[n] = f2bf(h);
  }
#pragma unroll
  for (int n = 16; n < 32; ++n) o[n] = 0;
  unsigned short* dst = h16 + (size_t)m * 32;
#pragma unroll
  for (int q = 0; q < 4; ++q) *(ushort8v*)(dst + q * 8) = *(const ushort8v*)(o + q * 8);
}

// ---------------- k4: 256x256 8-phase pipelined bf16 MFMA GEMM ----------------
// out = x16 @ WoD^T + h16 @ Wco^T + bz.  BM=BN=256, BK=64 (2 K-halves of 32),
// 8 waves (2x4), 128KB LDS = 2dbuf x 2kh x {A,B} x 16KB. Counted vmcnt(4) at
// phases 3/7 only; raw s_barrier + sched_barrier fences; setprio around MFMA.
// LDS swizzle: cb ^= ((r>>1)&3)<<4 (applied on pre-swizzled global src + ds_read).
__global__ __launch_bounds__(512, 2) void k4_gemm(
    const unsigned short* __restrict__ x16, const unsigned short* __restrict__ h16,
    const unsigned short* __restrict__ WoD16, const unsigned short* __restrict__ Wco16,
    const float* __restrict__ bz, float* __restrict__ C) {
  __shared__ __align__(16) char smem[131072];
  const int tid = threadIdx.x;
  const int swzid = (blockIdx.x & 7) * 64 + (blockIdx.x >> 3);  // bijective, 512%8==0
  const int by = swzid >> 2;   // 0..127
  const int bx = swzid & 3;    // 0..3
  const int lane = tid & 63;
  const int w = tid >> 6;
  const int wm = w >> 2, wn = w & 3;   // 2 x 4 wave grid
  const int p = lane & 15, g = lane >> 4;
  const int cbsw = (g * 16) ^ (((p >> 1) & 3) << 4);

  f32x4 acc[8][4];
#pragma unroll
  for (int i = 0; i < 8; ++i)
#pragma unroll
    for (int j = 0; j < 4; ++j) acc[i][j] = (f32x4){0.f, 0.f, 0.f, 0.f};

  // --- h-correction: one K=32 step straight from L2 ---
  {
    short8 ah[8], bh[4];
#pragma unroll
    for (int mi = 0; mi < 8; ++mi)
      ah[mi] = *(const short8*)(h16 + (size_t)(by * 256 + wm * 128 + mi * 16 + p) * 32 + g * 8);
#pragma unroll
    for (int ni = 0; ni < 4; ++ni)
      bh[ni] = *(const short8*)(Wco16 + (size_t)(bx * 256 + wn * 64 + ni * 16 + p) * 32 + g * 8);
#pragma unroll
    for (int mi = 0; mi < 8; ++mi)
#pragma unroll
      for (int ni = 0; ni < 4; ++ni)
        acc[mi][ni] = __builtin_amdgcn_mfma_f32_16x16x32_bf16(ah[mi], bh[ni],
                                                              acc[mi][ni], 0, 0, 0);
  }
  SB();

  // --- staging precompute: linear LDS dest, inverse-swizzled global source ---
  const char* Ag = (const char*)(x16 + (size_t)(by * 256) * DM);
  const char* Bg = (const char*)(WoD16 + (size_t)(bx * 256) * DM);
  const int L0 = tid * 16, L1 = 8192 + tid * 16;
  const int r0 = L0 >> 6, r1 = L1 >> 6;
  const size_t ga0 = (size_t)r0 * 2048 + ((L0 & 63) ^ (((r0 >> 1) & 3) << 4));
  const size_t ga1 = (size_t)r1 * 2048 + ((L1 & 63) ^ (((r1 >> 1) & 3) << 4));

#define STG_A(d, kh, t_)                                                        \
  do { const int ko_ = (t_) * 128 + (kh) * 64;                                  \
    gl_lds16(Ag + ga0 + ko_, smem + (d) * 32768 + (kh) * 16384 + L0);           \
    gl_lds16(Ag + ga1 + ko_, smem + (d) * 32768 + (kh) * 16384 + L1); } while (0)
#define STG_B(d, kh, t_)                                                        \
  do { const int ko_ = (t_) * 128 + (kh) * 64;                                  \
    gl_lds16(Bg + ga0 + ko_, smem + 65536 + (d) * 32768 + (kh) * 16384 + L0);   \
    gl_lds16(Bg + ga1 + ko_, smem + 65536 + (d) * 32768 + (kh) * 16384 + L1); } while (0)

#define PHASE(d, kh, mh, STAGE_STMT, VMSTMT)                                    \
  do {                                                                          \
    const char* ab_ = smem + (d) * 32768 + (kh) * 16384;                        \
    const char* bb_ = smem + 65536 + (d) * 32768 + (kh) * 16384;                \
    short8 af0 = *(const short8*)(ab_ + (wm * 128 + ((mh) * 4 + 0) * 16 + p) * 64 + cbsw); \
    short8 af1 = *(const short8*)(ab_ + (wm * 128 + ((mh) * 4 + 1) * 16 + p) * 64 + cbsw); \
    short8 af2 = *(const short8*)(ab_ + (wm * 128 + ((mh) * 4 + 2) * 16 + p) * 64 + cbsw); \
    short8 af3 = *(const short8*)(ab_ + (wm * 128 + ((mh) * 4 + 3) * 16 + p) * 64 + cbsw); \
    short8 bf0 = *(const short8*)(bb_ + (wn * 64 + 0 * 16 + p) * 64 + cbsw);    \
    short8 bf1 = *(const short8*)(bb_ + (wn * 64 + 1 * 16 + p) * 64 + cbsw);    \
    short8 bf2 = *(const short8*)(bb_ + (wn * 64 + 2 * 16 + p) * 64 + cbsw);    \
    short8 bf3 = *(const short8*)(bb_ + (wn * 64 + 3 * 16 + p) * 64 + cbsw);    \
    STAGE_STMT;                                                                 \
    bar();                                                                      \
    __builtin_amdgcn_s_setprio(1);                                              \
    acc[(mh)*4+0][0] = __builtin_amdgcn_mfma_f32_16x16x32_bf16(af0, bf0, acc[(mh)*4+0][0], 0, 0, 0); \
    acc[(mh)*4+0][1] = __builtin_amdgcn_mfma_f32_16x16x32_bf16(af0, bf1, acc[(mh)*4+0][1], 0, 0, 0); \
    acc[(mh)*4+0][2] = __builtin_amdgcn_mfma_f32_16x16x32_bf16(af0, bf2, acc[(mh)*4+0][2], 0, 0, 0); \
    acc[(mh)*4+0][3] = __builtin_amdgcn_mfma_f32_16x16x32_bf16(af0, bf3, acc[(mh)*4+0][3], 0, 0, 0); \
    acc[(mh)*4+1][0] = __builtin_amdgcn_mfma_f32_16x16x32_bf16(af1, bf0, acc[(mh)*4+1][0], 0, 0, 0); \
    acc[(mh)*4+1][1] = __builtin_amdgcn_mfma_f32_16x16x32_bf16(af1, bf1, acc[(mh)*4+1][1], 0, 0, 0); \
    acc[(mh)*4+1][2] = __builtin_amdgcn_mfma_f32_16x16x32_bf16(af1, bf2, acc[(mh)*4+1][2], 0, 0, 0); \
    acc[(mh)*4+1][3] = __builtin_amdgcn_mfma_f32_16x16x32_bf16(af1, bf3, acc[(mh)*4+1][3], 0, 0, 0); \
    acc[(mh)*4+2][0] = __builtin_amdgcn_mfma_f32_16x16x32_bf16(af2, bf0, acc[(mh)*4+2][0], 0, 0, 0); \
    acc[(mh)*4+2][1] = __builtin_amdgcn_mfma_f32_16x16x32_bf16(af2, bf1, acc[(mh)*4+2][1], 0, 0, 0); \
    acc[(mh)*4+2][2] = __builtin_amdgcn_mfma_f32_16x16x32_bf16(af2, bf2, acc[(mh)*4+2][2], 0, 0, 0); \
    acc[(mh)*4+2][3] = __builtin_amdgcn_mfma_f32_16x16x32_bf16(af2, bf3, acc[(mh)*4+2][3], 0, 0, 0); \
    acc[(mh)*4+3][0] = __builtin_amdgcn_mfma_f32_16x16x32_bf16(af3, bf0, acc[(mh)*4+3][0], 0, 0, 0); \
    acc[(mh)*4+3][1] = __builtin_amdgcn_mfma_f32_16x16x32_bf16(af3, bf1, acc[(mh)*4+3][1], 0, 0, 0); \
    acc[(mh)*4+3][2] = __builtin_amdgcn_mfma_f32_16x16x32_bf16(af3, bf2, acc[(mh)*4+3][2], 0, 0, 0); \
    acc[(mh)*4+3][3] = __builtin_amdgcn_mfma_f32_16x16x32_bf16(af3, bf3, acc[(mh)*4+3][3], 0, 0, 0); \
    __builtin_amdgcn_s_setprio(0);                                              \
    VMSTMT;                                                                     \
    bar();                                                                      \
  } while (0)

  // prologue: T0 fully + T1 Kh0; land T0 (oldest 4 units), 2 units in flight
  STG_A(0, 0, 0); STG_B(0, 0, 0); STG_A(0, 1, 0); STG_B(0, 1, 0);
  STG_A(1, 0, 1); STG_B(1, 0, 1);
  VMW4;
  bar();

#pragma unroll 1
  for (int i = 0; i < 8; ++i) {
    const int t1 = 2 * i + 1;
    const int t2 = (2 * i + 2 > 15) ? 15 : 2 * i + 2;   // tail: re-stage dead region
    const int t3 = (2 * i + 3 > 15) ? 15 : 2 * i + 3;
    PHASE(0, 0, 0, STG_A(1, 1, t1), VMNOP);
    PHASE(0, 0, 1, STG_B(1, 1, t1), VMNOP);
    PHASE(0, 1, 0, STG_A(0, 0, t2), VMNOP);
    PHASE(0, 1, 1, STG_B(0, 0, t2), VMW4);
    PHASE(1, 0, 0, STG_A(0, 1, t2), VMNOP);
    PHASE(1, 0, 1, STG_B(0, 1, t2), VMNOP);
    PHASE(1, 1, 0, STG_A(1, 0, t3), VMNOP);
    PHASE(1, 1, 1, STG_B(1, 0, t3), VMW4);
  }
  VMW0;
#undef PHASE
#undef STG_A
#undef STG_B

#pragma unroll
  for (int ni = 0; ni < 4; ++ni) {
    const int c0 = bx * 256 + wn * 64 + ni * 16 + p;
    const float bzv = bz[c0];
#pragma unroll
    for (int mi = 0; mi < 8; ++mi) {
      const int r0w = by * 256 + wm * 128 + mi * 16 + g * 4;
#pragma unroll
      for (int r = 0; r < 4; ++r)
        C[(size_t)(r0w + r) * DM + c0] = acc[mi][ni][r] + bzv;
    }
  }
}

// ---------------- launch ----------------
extern "C" void kernel_launch(void* const* d_in, const int* in_sizes, int n_in,
                              void* d_out, int out_size, void* d_ws, size_t ws_size,
                              hipStream_t stream) {
  const float* x  = (const float*)d_in[0];
  const float* A  = (const float*)d_in[1];
  const float* Wb = (const float*)d_in[2];
  const float* bb = (const float*)d_in[3];
  const float* Wc = (const float*)d_in[4];
  const float* bc = (const float*)d_in[5];
  const float* D  = (const float*)d_in[6];
  const float* Wt = (const float*)d_in[7];
  const float* bt = (const float*)d_in[8];
  const float* Wo = (const float*)d_in[9];
  const float* bo = (const float*)d_in[10];
  float* out = (float*)d_out;

  char* ws = (char*)d_ws;
  float* Ae            = (float*)(ws);                              // 2 MiB [B,N,S]
  float* Bu            = (float*)(ws + (2u << 20));                 // 2 MiB [B,N,S]
  unsigned short* h16  = (unsigned short*)(ws + (4u << 20));        // 2 MiB [M,32]
  unsigned short* WoD16= (unsigned short*)(ws + (6u << 20));        // 2 MiB
  unsigned short* Wco16= (unsigned short*)(ws + (8u << 20));        // 64 KiB
  float* bz            = (float*)(ws + (8u << 20) + (64u << 10));   // 4 KiB
  unsigned short* W16s = (unsigned short*)(ws + (8u << 20) + (68u << 10)); // 64 KiB
  float* agg_a         = (float*)(ws + (8u << 20) + (132u << 10));  // 8 KiB
  float* agg_u         = (float*)(ws + (8u << 20) + (140u << 10));  // 8 KiB
  unsigned short* x16  = (unsigned short*)(ws + (9u << 20));        // 64 MiB

  k0_prep<<<1056, 256, 0, stream>>>(Wo, D, Wc, bc, bo, WoD16, Wco16, bz, Wb, Wt, W16s);
  k1_proj<<<512, 256, 0, stream>>>(x, A, W16s, bb, bt, Ae, Bu, x16);
  k2a<<<512, 256, 0, stream>>>(Ae, Bu, agg_a, agg_u);
  k2c<<<128, 256, 0, stream>>>(Ae, Bu, agg_a, agg_u, h16);
  k4_gemm<<<512, 512, 0, stream>>>(x16, h16, WoD16, Wco16, bz, out);
}

// Round 5
// 342.252 us; speedup vs baseline: 1.3042x; 1.0401x over previous
//
#include <hip/hip_runtime.h>
#include <hip/hip_bf16.h>
#include <cstdint>
#include <cstddef>

#define B_SZ 8
#define S_SZ 4096
#define DM   1024
#define NS   16
#define M_SZ (B_SZ * S_SZ)  // 32768

typedef __attribute__((ext_vector_type(4))) float f32x4;
typedef __attribute__((ext_vector_type(8))) short short8;
typedef __attribute__((ext_vector_type(4))) unsigned short ushort4v;
typedef __attribute__((ext_vector_type(8))) unsigned short ushort8v;

__device__ __forceinline__ unsigned short f2bf(float f) {
  unsigned u = __float_as_uint(f);
  u += 0x7fffu + ((u >> 16) & 1u);   // RNE
  return (unsigned short)(u >> 16);
}

__device__ __forceinline__ short8 cvt8(f32x4 a, f32x4 b) {
  short8 r;
  r[0] = (short)f2bf(a[0]); r[1] = (short)f2bf(a[1]);
  r[2] = (short)f2bf(a[2]); r[3] = (short)f2bf(a[3]);
  r[4] = (short)f2bf(b[0]); r[5] = (short)f2bf(b[1]);
  r[6] = (short)f2bf(b[2]); r[7] = (short)f2bf(b[3]);
  return r;
}

__device__ __forceinline__ void gl_lds16(const void* g, void* l) {
  __builtin_amdgcn_global_load_lds(
      (const __attribute__((address_space(1))) void*)g,
      (__attribute__((address_space(3))) void*)l, 16, 0, 0);
}

#define SB() __builtin_amdgcn_sched_barrier(0)
__device__ __forceinline__ void bar() { SB(); __builtin_amdgcn_s_barrier(); SB(); }
#define VMW4 asm volatile("s_waitcnt vmcnt(4)" ::: "memory")
#define VMW0 asm volatile("s_waitcnt vmcnt(0)" ::: "memory")

// ---------------- k0_prep (+ folded kW) ----------------
__global__ __launch_bounds__(256) void k0_prep(
    const float* __restrict__ Wo, const float* __restrict__ D,
    const float* __restrict__ Wc, const float* __restrict__ bc,
    const float* __restrict__ bo, unsigned short* __restrict__ WoD16,
    unsigned short* __restrict__ Wco16, float* __restrict__ bz,
    const float* __restrict__ Wb, const float* __restrict__ Wt,
    unsigned short* __restrict__ W16s) {
  const int t = threadIdx.x;
  if (blockIdx.x >= 1024) {   // kW part
    const int col = blockIdx.x - 1024;
    f32x4 a = {0.f, 0.f, 0.f, 0.f};
    if (col < 16)       a = *(const f32x4*)(Wb + (size_t)col * DM + t * 4);
    else if (col == 16) a = *(const f32x4*)(Wt + t * 4);
    ushort4v u;
#pragma unroll
    for (int i = 0; i < 4; ++i) u[i] = f2bf(a[i]);
    *(ushort4v*)((char*)W16s + ((col * 2048 + t * 8) ^ ((col & 7) << 4))) = u;
    return;
  }
  const int o = blockIdx.x;
  const float* wor = Wo + (size_t)o * DM;

  f32x4 wv = *(const f32x4*)(wor + t * 4);
  f32x4 dv = *(const f32x4*)(D + t * 4);
  ushort4v u;
#pragma unroll
  for (int i = 0; i < 4; ++i) u[i] = f2bf(wv[i] * dv[i]);
  *(ushort4v*)(WoD16 + (size_t)o * DM + t * 4) = u;

  const int n = t & 15, ds = t >> 4;
  float s = 0.f;
  const float* wod = wor + ds * 64;
  const float* wcd = Wc + (size_t)(ds * 64) * NS + n;
#pragma unroll 8
  for (int j = 0; j < 64; ++j) s += wod[j] * wcd[j * NS];

  f32x4 bcv = *(const f32x4*)(bc + t * 4);
  float pb = wv[0] * bcv[0] + wv[1] * bcv[1] + wv[2] * bcv[2] + wv[3] * bcv[3];

  __shared__ float red[16][17];
  __shared__ float redb[256];
  red[n][ds] = s;
  redb[t] = pb;
  __syncthreads();
  if (t < 16) {
    float acc = 0.f;
#pragma unroll
    for (int k = 0; k < 16; ++k) acc += red[t][k];
    Wco16[(size_t)o * 32 + t] = f2bf(acc);
    Wco16[(size_t)o * 32 + 16 + t] = 0;
  }
  if (t < 64) {
    float s4 = redb[t] + redb[t + 64] + redb[t + 128] + redb[t + 192];
#pragma unroll
    for (int mb = 1; mb < 64; mb <<= 1) s4 += __shfl_xor(s4, mb, 64);
    if (t == 0) bz[o] = bo[o] + s4;
  }
}

// ---------------- k1: MFMA skinny GEMM: Bu/z + x->bf16 ----------------
__global__ __launch_bounds__(256) void k1_proj(
    const float* __restrict__ x, const float* __restrict__ A,
    const unsigned short* __restrict__ W16s,
    const float* __restrict__ bb, const float* __restrict__ bt,
    float* __restrict__ Ae, float* __restrict__ Bu,
    unsigned short* __restrict__ x16) {
  __shared__ __align__(16) char Wlds[65536];
  __shared__ float Bu_s[16][65];
  __shared__ float z_s[64];
  const int tid = threadIdx.x, lane = tid & 63, w = tid >> 6;
  const int p = lane & 15, g = lane >> 4;

#pragma unroll
  for (int i = 0; i < 16; ++i)
    gl_lds16((const char*)W16s + (w * 16 + i) * 1024 + lane * 16,
             Wlds + (w * 16 + i) * 1024);
  __syncthreads();

  const int m0 = blockIdx.x * 64;
  const int m = m0 + w * 16 + p;
  const float* xp = x + (size_t)m * DM;
  unsigned short* xo = x16 + (size_t)m * DM;
  f32x4 acc0 = {0.f, 0.f, 0.f, 0.f}, acc1 = {0.f, 0.f, 0.f, 0.f};
  const int cb0 = p * 2048;
  const int cb1 = (16 + p) * 2048;
  const int sw0 = (p & 7) << 4;

#pragma unroll 4
  for (int kk = 0; kk < 32; ++kk) {
    const int k0 = kk * 32 + g * 8;
    f32x4 xa = *(const f32x4*)(xp + k0);
    f32x4 xb = *(const f32x4*)(xp + k0 + 4);
    short8 af = cvt8(xa, xb);
    *(short8*)(xo + k0) = af;
    const int kb = kk * 64 + g * 16;
    short8 b0 = *(const short8*)(Wlds + ((cb0 + kb) ^ sw0));
    short8 b1 = *(const short8*)(Wlds + ((cb1 + kb) ^ sw0));
    acc0 = __builtin_amdgcn_mfma_f32_16x16x32_bf16(af, b0, acc0, 0, 0, 0);
    acc1 = __builtin_amdgcn_mfma_f32_16x16x32_bf16(af, b1, acc1, 0, 0, 0);
  }

  const float bbn = bb[p];
#pragma unroll
  for (int r = 0; r < 4; ++r) Bu_s[p][w * 16 + g * 4 + r] = acc0[r] + bbn;
  if (p == 0) {
#pragma unroll
    for (int r = 0; r < 4; ++r) z_s[w * 16 + g * 4 + r] = acc1[r];
  }
  __syncthreads();

  const int b_idx = m0 >> 12;
  const int s0 = m0 & (S_SZ - 1);
  const int n = tid >> 4, j0 = (tid & 15) * 4;
  const float an = A[n];
  const float bt0 = bt[0];
  size_t off = ((size_t)(b_idx * NS + n)) * S_SZ + s0 + j0;
#pragma unroll
  for (int jj = 0; jj < 4; ++jj) {
    float z = z_s[j0 + jj] + bt0;
    float delta = 1.f / (1.f + __expf(-z));
    delta = delta * 0.99f + 0.01f;
    Ae[off + jj] = __expf(an * delta);
    Bu[off + jj] = Bu_s[n][j0 + jj];
  }
}

// ---------------- k2a: per-chunk local affine scan (in-place) ----------------
__global__ __launch_bounds__(256) void k2a(float* __restrict__ Ae, float* __restrict__ Bu,
                                           float* __restrict__ agg_a, float* __restrict__ agg_u) {
  const int l = threadIdx.x & 63, w = threadIdx.x >> 6;
  const int cid = blockIdx.x * 4 + w;
  float* ap = Ae + (size_t)cid * 256;
  float* up = Bu + (size_t)cid * 256;
  float ca = 1.f, cu = 0.f;
#pragma unroll 1
  for (int seg = 0; seg < 4; ++seg) {
    float a = ap[seg * 64 + l], u = up[seg * 64 + l];
#pragma unroll
    for (int off = 1; off < 64; off <<= 1) {
      float aL = __shfl_up(a, off, 64);
      float uL = __shfl_up(u, off, 64);
      if (l >= off) { u = a * uL + u; a = aL * a; }
    }
    float At = ca * a, Ut = a * cu + u;
    ap[seg * 64 + l] = At;
    up[seg * 64 + l] = Ut;
    ca = __shfl(At, 63, 64);
    cu = __shfl(Ut, 63, 64);
  }
  if (l == 0) { agg_a[cid] = ca; agg_u[cid] = cu; }
}

// ---------------- k2c: carries + h16 [M,32] bf16 (256 blocks x 128 thr) ----------------
__global__ __launch_bounds__(128) void k2c(const float* __restrict__ Ae,
                                           const float* __restrict__ Bu,
                                           const float* __restrict__ agg_a,
                                           const float* __restrict__ agg_u,
                                           unsigned short* __restrict__ h16) {
  const int t = threadIdx.x;
  const int m = blockIdx.x * 128 + t;
  const int b = m >> 12, s = m & 4095, c = s >> 8;
  __shared__ float cp_s[16];
  if (t < 16) {
    float cu = 0.f;
    const int base = (b * 16 + t) * 16;
    for (int c2 = 0; c2 < c; ++c2) cu = agg_a[base + c2] * cu + agg_u[base + c2];
    cp_s[t] = cu;
  }
  __syncthreads();
  unsigned short o[32];
#pragma unroll
  for (int n = 0; n < 16; ++n) {
    size_t idx = ((size_t)(b * 16 + n)) * 4096 + s;
    float h = Ae[idx] * cp_s[n] + Bu[idx];
    o[n] = f2bf(h);
  }
#pragma unroll
  for (int n = 16; n < 32; ++n) o[n] = 0;
  unsigned short* dst = h16 + (size_t)m * 32;
#pragma unroll
  for (int q = 0; q < 4; ++q) *(ushort8v*)(dst + q * 8) = *(const ushort8v*)(o + q * 8);
}

// ---------------- k4: 256x256 reg-dbuf 4-phase bf16 MFMA GEMM ----------------
// Phase = 1 K-chunk (32 elems). Per phase: issue 12 ds_reads for NEXT chunk's
// frags (overlap MFMA via compiler lgkmcnt(12)) + 4 gl_lds staging chunk+3 ->
// sched_barrier -> 32 MFMA on current frags (setprio) -> vmcnt(4) -> s_barrier.
// Regions: chunk c lives in 16KB region c%4 (A at r*16K, B at 64K + r*16K).
// Ledger: stage->read dist 2 phases; vmcnt(4)+bar at each phase end drains
// 2-phase-old staging for all waves (RAW); region reads finish before the bar
// preceding its re-stage (WAR).
__global__ __launch_bounds__(512, 2) void k4_gemm(
    const unsigned short* __restrict__ x16, const unsigned short* __restrict__ h16,
    const unsigned short* __restrict__ WoD16, const unsigned short* __restrict__ Wco16,
    const float* __restrict__ bz, float* __restrict__ C) {
  __shared__ __align__(16) char smem[131072];
  const int tid = threadIdx.x;
  const int swzid = (blockIdx.x & 7) * 64 + (blockIdx.x >> 3);  // bijective, 512%8==0
  const int by = swzid >> 2;   // 0..127
  const int bx = swzid & 3;    // 0..3
  const int lane = tid & 63;
  const int w = tid >> 6;
  const int wm = w >> 2, wn = w & 3;   // 2 x 4 wave grid
  const int p = lane & 15, g = lane >> 4;
  const int cbsw = (g * 16) ^ (((p >> 1) & 3) << 4);

  f32x4 acc[8][4];
#pragma unroll
  for (int i = 0; i < 8; ++i)
#pragma unroll
    for (int j = 0; j < 4; ++j) acc[i][j] = (f32x4){0.f, 0.f, 0.f, 0.f};

  // --- h-correction: one K=32 step straight from L2 ---
  {
    short8 ah[8], bh[4];
#pragma unroll
    for (int mi = 0; mi < 8; ++mi)
      ah[mi] = *(const short8*)(h16 + (size_t)(by * 256 + wm * 128 + mi * 16 + p) * 32 + g * 8);
#pragma unroll
    for (int ni = 0; ni < 4; ++ni)
      bh[ni] = *(const short8*)(Wco16 + (size_t)(bx * 256 + wn * 64 + ni * 16 + p) * 32 + g * 8);
#pragma unroll
    for (int mi = 0; mi < 8; ++mi)
#pragma unroll
      for (int ni = 0; ni < 4; ++ni)
        acc[mi][ni] = __builtin_amdgcn_mfma_f32_16x16x32_bf16(ah[mi], bh[ni],
                                                              acc[mi][ni], 0, 0, 0);
  }
  SB();

  // --- staging: linear LDS dest, inverse-swizzled global source ---
  const char* Ag = (const char*)(x16 + (size_t)(by * 256) * DM);
  const char* Bg = (const char*)(WoD16 + (size_t)(bx * 256) * DM);
  const int L0 = tid * 16, L1 = 8192 + tid * 16;
  const int r0 = L0 >> 6, r1 = L1 >> 6;
  const size_t ga0 = (size_t)r0 * 2048 + ((L0 & 63) ^ (((r0 >> 1) & 3) << 4));
  const size_t ga1 = (size_t)r1 * 2048 + ((L1 & 63) ^ (((r1 >> 1) & 3) << 4));

#define STG(r_, c_)                                                            \
  do { const int ko_ = (c_) * 64;                                              \
    gl_lds16(Ag + ga0 + ko_, smem + (r_) * 16384 + L0);                        \
    gl_lds16(Ag + ga1 + ko_, smem + (r_) * 16384 + L1);                        \
    gl_lds16(Bg + ga0 + ko_, smem + 65536 + (r_) * 16384 + L0);                \
    gl_lds16(Bg + ga1 + ko_, smem + 65536 + (r_) * 16384 + L1); } while (0)

  short8 fA[2][8];
  short8 fB[2][4];

#define LOADFRAG(S, RG)                                                        \
  do {                                                                         \
    const char* ar_ = smem + (RG) * 16384 + (wm * 128 + p) * 64 + cbsw;        \
    const char* br_ = smem + 65536 + (RG) * 16384 + (wn * 64 + p) * 64 + cbsw; \
    fA[S][0] = *(const short8*)(ar_ + 0 * 1024);                               \
    fA[S][1] = *(const short8*)(ar_ + 1 * 1024);                               \
    fA[S][2] = *(const short8*)(ar_ + 2 * 1024);                               \
    fA[S][3] = *(const short8*)(ar_ + 3 * 1024);                               \
    fA[S][4] = *(const short8*)(ar_ + 4 * 1024);                               \
    fA[S][5] = *(const short8*)(ar_ + 5 * 1024);                               \
    fA[S][6] = *(const short8*)(ar_ + 6 * 1024);                               \
    fA[S][7] = *(const short8*)(ar_ + 7 * 1024);                               \
    fB[S][0] = *(const short8*)(br_ + 0 * 1024);                               \
    fB[S][1] = *(const short8*)(br_ + 1 * 1024);                               \
    fB[S][2] = *(const short8*)(br_ + 2 * 1024);                               \
    fB[S][3] = *(const short8*)(br_ + 3 * 1024);                               \
  } while (0)

#define MM1(S, MI)                                                                            \
  acc[MI][0] = __builtin_amdgcn_mfma_f32_16x16x32_bf16(fA[S][MI], fB[S][0], acc[MI][0], 0, 0, 0); \
  acc[MI][1] = __builtin_amdgcn_mfma_f32_16x16x32_bf16(fA[S][MI], fB[S][1], acc[MI][1], 0, 0, 0); \
  acc[MI][2] = __builtin_amdgcn_mfma_f32_16x16x32_bf16(fA[S][MI], fB[S][2], acc[MI][2], 0, 0, 0); \
  acc[MI][3] = __builtin_amdgcn_mfma_f32_16x16x32_bf16(fA[S][MI], fB[S][3], acc[MI][3], 0, 0, 0);

#define MM(S)                                                                  \
  do { __builtin_amdgcn_s_setprio(1);                                          \
    MM1(S, 0) MM1(S, 1) MM1(S, 2) MM1(S, 3)                                    \
    MM1(S, 4) MM1(S, 5) MM1(S, 6) MM1(S, 7)                                    \
    __builtin_amdgcn_s_setprio(0); } while (0)

#define PHASE(J, S, c3)                                                        \
  do {                                                                         \
    LOADFRAG(1 - (S), ((J) + 1) & 3);                                          \
    STG(((J) + 3) & 3, c3);                                                    \
    SB();                                                                      \
    MM(S);                                                                     \
    VMW4;                                                                      \
    bar();                                                                     \
  } while (0)

  // prologue: stage chunks 0,1,2; drain 0,1; load frags chunk 0
  STG(0, 0); STG(1, 1); STG(2, 2);
  VMW4;
  bar();
  LOADFRAG(0, 0);

#pragma unroll 1
  for (int it = 0; it < 8; ++it) {
    const int c0_ = it * 4;
    const int t0 = (c0_ + 3 > 31) ? 31 : c0_ + 3;
    const int t1 = (c0_ + 4 > 31) ? 31 : c0_ + 4;
    const int t2 = (c0_ + 5 > 31) ? 31 : c0_ + 5;
    const int t3 = (c0_ + 6 > 31) ? 31 : c0_ + 6;
    PHASE(0, 0, t0);
    PHASE(1, 1, t1);
    PHASE(2, 0, t2);
    PHASE(3, 1, t3);
  }
  VMW0;
#undef PHASE
#undef MM
#undef MM1
#undef LOADFRAG
#undef STG

#pragma unroll
  for (int ni = 0; ni < 4; ++ni) {
    const int c0 = bx * 256 + wn * 64 + ni * 16 + p;
    const float bzv = bz[c0];
#pragma unroll
    for (int mi = 0; mi < 8; ++mi) {
      const int r0w = by * 256 + wm * 128 + mi * 16 + g * 4;
#pragma unroll
      for (int r = 0; r < 4; ++r)
        C[(size_t)(r0w + r) * DM + c0] = acc[mi][ni][r] + bzv;
    }
  }
}

// ---------------- launch ----------------
extern "C" void kernel_launch(void* const* d_in, const int* in_sizes, int n_in,
                              void* d_out, int out_size, void* d_ws, size_t ws_size,
                              hipStream_t stream) {
  const float* x  = (const float*)d_in[0];
  const float* A  = (const float*)d_in[1];
  const float* Wb = (const float*)d_in[2];
  const float* bb = (const float*)d_in[3];
  const float* Wc = (const float*)d_in[4];
  const float* bc = (const float*)d_in[5];
  const float* D  = (const float*)d_in[6];
  const float* Wt = (const float*)d_in[7];
  const float* bt = (const float*)d_in[8];
  const float* Wo = (const float*)d_in[9];
  const float* bo = (const float*)d_in[10];
  float* out = (float*)d_out;

  char* ws = (char*)d_ws;
  float* Ae            = (float*)(ws);                              // 2 MiB [B,N,S]
  float* Bu            = (float*)(ws + (2u << 20));                 // 2 MiB [B,N,S]
  unsigned short* h16  = (unsigned short*)(ws + (4u << 20));        // 2 MiB [M,32]
  unsigned short* WoD16= (unsigned short*)(ws + (6u << 20));        // 2 MiB
  unsigned short* Wco16= (unsigned short*)(ws + (8u << 20));        // 64 KiB
  float* bz            = (float*)(ws + (8u << 20) + (64u << 10));   // 4 KiB
  unsigned short* W16s = (unsigned short*)(ws + (8u << 20) + (68u << 10)); // 64 KiB
  float* agg_a         = (float*)(ws + (8u << 20) + (132u << 10));  // 8 KiB
  float* agg_u         = (float*)(ws + (8u << 20) + (140u << 10));  // 8 KiB
  unsigned short* x16  = (unsigned short*)(ws + (9u << 20));        // 64 MiB

  k0_prep<<<1056, 256, 0, stream>>>(Wo, D, Wc, bc, bo, WoD16, Wco16, bz, Wb, Wt, W16s);
  k1_proj<<<512, 256, 0, stream>>>(x, A, W16s, bb, bt, Ae, Bu, x16);
  k2a<<<512, 256, 0, stream>>>(Ae, Bu, agg_a, agg_u);
  k2c<<<256, 128, 0, stream>>>(Ae, Bu, agg_a, agg_u, h16);
  k4_gemm<<<512, 512, 0, stream>>>(x16, h16, WoD16, Wco16, bz, out);
}